// Round 6
// baseline (472.447 us; speedup 1.0000x reference)
//
#include <hip/hip_runtime.h>
#include <hip/hip_bf16.h>

using bf16x8 = __attribute__((ext_vector_type(8))) short;
using f32x4  = __attribute__((ext_vector_type(4))) float;

#define MFMA16(a, b, c) __builtin_amdgcn_mfma_f32_16x16x32_bf16((a), (b), (c), 0, 0, 0)

__device__ __forceinline__ short f2b(float f) {   // RNE bf16
    unsigned u = __builtin_bit_cast(unsigned, f);
    u = (u + 0x7fffu + ((u >> 16) & 1u)) >> 16;
    return (short)u;
}
__device__ __forceinline__ short pkb(float f) {   // round-to-nearest, ties away
    return (short)((__builtin_bit_cast(unsigned, f) + 0x8000u) >> 16);
}
__device__ __forceinline__ unsigned pk2(float lo, float hi) {  // two bf16 -> dword
    return (unsigned)(unsigned short)pkb(lo) | ((unsigned)(unsigned short)pkb(hi) << 16);
}
__device__ __forceinline__ void gl_lds16(const short* g, short* l) {
    __builtin_amdgcn_global_load_lds(
        (const __attribute__((address_space(1))) unsigned int*)g,
        (__attribute__((address_space(3))) unsigned int*)l, 16, 0, 0);
}

// ---------------- weight cast kernel (x-cast fused into gemm_qkv) ----------------
__global__ __launch_bounds__(256)
void cast_w_kernel(const float* __restrict__ wqkv, const float* __restrict__ wproj,
                   short* __restrict__ wqT, short* __restrict__ wpT) {
    const int t = blockIdx.x * 256 + threadIdx.x;
    if (t < 768 * 256) {
        const int n = t >> 8, k = t & 255;
        float v = wqkv[k * 768 + n];
        if (n < 256) v *= 0.17677669529663687f;    // fold 1/sqrt(hd) into q columns
        wqT[t] = f2b(v);
    } else {
        const int u = t - 768 * 256;               // u < 65536
        const int n = u >> 8, k = u & 255;
        wpT[u] = f2b(wproj[k * 256 + n]);
    }
}

// ---------------- QKV GEMM with fused fp32->bf16 A-cast ----------------
// A reg-staged from x (fp32); LOADA issue point pinned BEFORE COMPUTE via sched_barrier(0)
// (R5 showed the compiler sinks the loads to CVTW otherwise: VGPR stayed 60, dur +68us).
// CVTW after COMPUTE: the auto-vmcnt wait then has the whole MFMA phase as cover.
__global__ __launch_bounds__(256)
void gemm_qkv_kernel(const float* __restrict__ X, const short* __restrict__ Bt,
                     short* __restrict__ qkvL, short* __restrict__ qkvG) {
    __shared__ __align__(16) short smem[128 * 136];  // 34816 B: staging 2x8KB dbuf, epilogue Cs
    const int tid  = threadIdx.x;
    const int lane = tid & 63, wave = tid >> 6;
    const int wm = wave >> 1, wn = wave & 1;
    const int quad = lane >> 4, l16 = lane & 15;
    const int id = blockIdx.x;
    const int qq = id >> 3, xcd = id & 7;
    const int m0 = (xcd * 128 + qq / 6) * 128;
    const int n0 = (qq % 6) * 128;

    const f32x4 zf = {0.f, 0.f, 0.f, 0.f};
    f32x4 acc[4][4];
#pragma unroll
    for (int i = 0; i < 4; ++i)
#pragma unroll
        for (int j = 0; j < 4; ++j) acc[i][j] = zf;

    const int srow = wave * 16 + (lane >> 2);
    const int sws  = ((lane & 3) ^ ((lane >> 3) & 3)) * 8;   // swizzled 8-short chunk; (lane>>3)&3 == (srow>>1)&3
    const float* Xp = X + (long)(m0 + srow) * 256 + (lane & 3) * 8;   // linear global fp32
    const short* Bp = Bt + (long)(n0 + srow) * 256 + sws;             // pre-swizzled global bf16

    float4 a0, a1, a2, a3;                                   // in-flight A tile (srow, srow+64)
    auto LOADA = [&](int kt) {
        const float* p = Xp + kt * 32;
        a0 = *(const float4*)p;
        a1 = *(const float4*)(p + 4);
        a2 = *(const float4*)(p + 64 * 256);
        a3 = *(const float4*)(p + 64 * 256 + 4);
    };
    auto CVTW = [&](int buf) {                               // convert + swizzled LDS write
        short* As = smem + buf * 8192;
        bf16x8 r0, r1;
        r0[0] = f2b(a0.x); r0[1] = f2b(a0.y); r0[2] = f2b(a0.z); r0[3] = f2b(a0.w);
        r0[4] = f2b(a1.x); r0[5] = f2b(a1.y); r0[6] = f2b(a1.z); r0[7] = f2b(a1.w);
        r1[0] = f2b(a2.x); r1[1] = f2b(a2.y); r1[2] = f2b(a2.z); r1[3] = f2b(a2.w);
        r1[4] = f2b(a3.x); r1[5] = f2b(a3.y); r1[6] = f2b(a3.z); r1[7] = f2b(a3.w);
        *(bf16x8*)&As[srow * 32 + sws]        = r0;
        *(bf16x8*)&As[(srow + 64) * 32 + sws] = r1;          // (srow+64)>>1 keeps bits 1..2
    };
    auto STAGEB = [&](int buf, int kt) {
        short* lB = smem + buf * 8192 + 4096 + wave * 512;
        const int off = kt * 32;
        gl_lds16(Bp + off,            lB);
        gl_lds16(Bp + 64 * 256 + off, lB + 2048);
    };
    const int sw = (l16 >> 1) & 3;                           // read-side swizzle
    auto COMPUTE = [&](int buf) {
        const short* As = smem + buf * 8192;
        const short* Bs = As + 4096;
        bf16x8 af[4], bfr[4];
#pragma unroll
        for (int i = 0; i < 4; ++i)
            af[i] = *(const bf16x8*)&As[(wm * 64 + i * 16 + l16) * 32 + ((quad ^ sw) * 8)];
#pragma unroll
        for (int j = 0; j < 4; ++j)
            bfr[j] = *(const bf16x8*)&Bs[(wn * 64 + j * 16 + l16) * 32 + ((quad ^ sw) * 8)];
#pragma unroll
        for (int i = 0; i < 4; ++i)
#pragma unroll
            for (int j = 0; j < 4; ++j)
                acc[i][j] = MFMA16(af[i], bfr[j], acc[i][j]);
    };

    LOADA(0);
    STAGEB(0, 0);
    CVTW(0);                           // compiler waits the 4 A-loads (vmcnt), writes buf0
    for (int kt = 0; kt < 8; ++kt) {
        __syncthreads();               // publishes buf(kt): B gl_lds drained, A ds_writes visible
        if (kt < 7) {
            LOADA(kt + 1);             // issue early...
            STAGEB((kt + 1) & 1, kt + 1);
            __builtin_amdgcn_sched_barrier(0);   // ...and PIN the issue point (R5 fix)
        }
        COMPUTE(kt & 1);
        if (kt < 7) CVTW((kt + 1) & 1);   // a-regs landed during COMPUTE; write next buf
    }

    // ---- epilogue phase 1: acc -> Cs[128 rows][136] as bf16 ----
    __syncthreads();                            // buffers fully consumed; reuse as Cs
    short* Cs = smem;
    {
        const int crow = wm * 64 + quad * 4;
        const int ccol = wn * 64 + l16;
#pragma unroll
        for (int i = 0; i < 4; ++i)
#pragma unroll
            for (int j = 0; j < 4; ++j)
#pragma unroll
                for (int r = 0; r < 4; ++r)
                    Cs[(crow + i * 16 + r) * 136 + ccol + j * 16] = pkb(acc[i][j][r]);
    }
    __syncthreads();

    // ---- epilogue phase 2: coalesced chunk stores ----
    const int part = n0 >> 8;                   // 0=q 1=k 2=v (block-uniform)
    const bool isLocal = ((n0 >> 7) & 1) == 0;  // heads 0..3 vs 4..7
    const int b    = m0 >> 14;
    const int hrow = (m0 >> 7) & 127;
    if (isLocal) {
        short* dst0 = qkvL + part * 2048;
        const int win_hi = (hrow >> 3) << 4;
        const int ti0    = (hrow & 7) * 8;
        const int t  = lane >> 3;               // 0..7   (ti within chunk)
        const int s4 = (lane & 7) * 4;          // shorts within 32-ch row
#pragma unroll
        for (int c = 0; c < 16; ++c) {
            const int idx = wave * 16 + c;
            const int wi = idx >> 2, h = idx & 3;
            const ushort4 v = *(const ushort4*)&Cs[(wi * 8 + t) * 136 + h * 32 + s4];
            short* dp = dst0 + (long)(((b << 8) | (win_hi | wi)) * 4 + h) * 6144 + ti0 * 32;
            *(ushort4*)&dp[lane * 4] = v;       // 512 B contiguous per chunk
        }
    } else {
        short* dst0 = qkvG + part * 8192;
        const int pos0 = (hrow & 7) * 8;
        const int tib  = (hrow >> 3) * 16;
        const int tt = lane >> 2;               // 0..15  (ti within chunk)
        const int s8 = (lane & 3) * 8;
#pragma unroll
        for (int c = 0; c < 8; ++c) {
            const int idx = wave * 8 + c;
            const int p = idx >> 2, h = idx & 3;
            const bf16x8 v = *(const bf16x8*)&Cs[(p + tt * 8) * 136 + h * 32 + s8];
            short* dp = dst0 + (long)(((b << 6) | (pos0 + p)) * 4 + h) * 24576 + tib * 32;
            *(bf16x8*)&dp[lane * 8] = v;        // 1 KB contiguous per chunk
        }
    }
}

// ---------------- proj GEMM: [131072 x 256] x [256 x 256]^T + bias, fp32 out ----------------
__global__ __launch_bounds__(256)
void gemm_proj_kernel(const short* __restrict__ A, const short* __restrict__ Bt,
                      float* __restrict__ C, const float* __restrict__ bias) {
    __shared__ __align__(16) short smem[16384];  // 2 x (A 4096 | B 4096)
    const int tid  = threadIdx.x;
    const int lane = tid & 63, wave = tid >> 6;
    const int wm = wave >> 1, wn = wave & 1;
    const int quad = lane >> 4, l16 = lane & 15;
    const int id = blockIdx.x;
    const int qq = id >> 3, xcd = id & 7;
    const int m0 = (xcd * 128 + (qq >> 1)) * 128;
    const int n0 = (qq & 1) * 128;

    const f32x4 zf = {0.f, 0.f, 0.f, 0.f};
    f32x4 acc[4][4];
#pragma unroll
    for (int i = 0; i < 4; ++i)
#pragma unroll
        for (int j = 0; j < 4; ++j) acc[i][j] = zf;

    const int srow = wave * 16 + (lane >> 2);
    const int scol = ((lane & 3) ^ ((lane >> 3) & 3)) * 8;   // pre-swizzled global source
    const short* Ap = A  + (long)(m0 + srow) * 256 + scol;
    const short* Bp = Bt + (long)(n0 + srow) * 256 + scol;

    auto STAGE = [&](int buf, int kt) {
        short* lA = smem + buf * 8192 + wave * 512;
        const int off = kt * 32;
        gl_lds16(Ap + off,            lA);
        gl_lds16(Ap + 64 * 256 + off, lA + 2048);
        gl_lds16(Bp + off,            lA + 4096);
        gl_lds16(Bp + 64 * 256 + off, lA + 6144);
    };
    const int sw = (l16 >> 1) & 3;
    auto COMPUTE = [&](int buf) {
        const short* As = smem + buf * 8192;
        const short* Bs = As + 4096;
        bf16x8 af[4], bfr[4];
#pragma unroll
        for (int i = 0; i < 4; ++i)
            af[i] = *(const bf16x8*)&As[(wm * 64 + i * 16 + l16) * 32 + ((quad ^ sw) * 8)];
#pragma unroll
        for (int j = 0; j < 4; ++j)
            bfr[j] = *(const bf16x8*)&Bs[(wn * 64 + j * 16 + l16) * 32 + ((quad ^ sw) * 8)];
#pragma unroll
        for (int i = 0; i < 4; ++i)
#pragma unroll
            for (int j = 0; j < 4; ++j)
                acc[i][j] = MFMA16(af[i], bfr[j], acc[i][j]);
    };

    STAGE(0, 0);
    for (int kt = 0; kt < 8; ++kt) {
        __syncthreads();
        if (kt < 7) STAGE((kt + 1) & 1, kt + 1);
        COMPUTE(kt & 1);
    }

#pragma unroll
    for (int i = 0; i < 4; ++i)
#pragma unroll
        for (int r = 0; r < 4; ++r) {
            const long row = m0 + wm * 64 + i * 16 + quad * 4 + r;
#pragma unroll
            for (int j = 0; j < 4; ++j) {
                const int col = n0 + wn * 64 + j * 16 + l16;
                C[row * 256 + col] = acc[i][j][r] + bias[col];
            }
        }
}

// ---------------- fused attention kernel ----------------
// blocks [0,2048): grid (global) attention, heads 4..7, seq=256, 1 block/seq-head
// blocks [2048,4096): window (local) attention, heads 0..3, seq=64, 1 wave/seq-head
__global__ __launch_bounds__(256)
void attn_kernel(const short* __restrict__ qkvL, const short* __restrict__ qkvG,
                 short* __restrict__ attn) {
    __shared__ __align__(16) short smem[13824];   // 27648 B -> 5 blocks/CU
    const int tid  = threadIdx.x;
    const int lane = tid & 63, wave = tid >> 6;
    const int quad = lane >> 4, l16 = lane & 15;
    const bf16x8 vone = {0x3F80, 0x3F80, 0x3F80, 0x3F80, 0x3F80, 0x3F80, 0x3F80, 0x3F80};
    const f32x4 zf = {0.f, 0.f, 0.f, 0.f};
    const bool evenL = (l16 & 1) == 0;

    if (blockIdx.x < 2048) {
        // ================= grid (global) attention =================
        short* sVT = smem;                 // [32*264]
        short* sP  = smem + 8448 + wave * 1152;   // per-wave [16*72]
        const int sh   = blockIdx.x;       // < 2048
        const int head = sh & 3;
        const int pos  = (sh >> 2) & 63;
        const int b    = sh >> 8;
        const int base_tok = b * 16384 + (pos >> 3) * 128 + (pos & 7);
        const int ch = (4 + head) * 32;
        const short* qb = qkvG + (long)sh * 24576;
        const short* kb = qb + 8192;
        const short* vp = qb + 16384;

        // stage V^T: thread = token (coalesced)
        {
            bf16x8 v0 = *(const bf16x8*)(vp + tid * 32);
            bf16x8 v1 = *(const bf16x8*)(vp + tid * 32 + 8);
            bf16x8 v2 = *(const bf16x8*)(vp + tid * 32 + 16);
            bf16x8 v3 = *(const bf16x8*)(vp + tid * 32 + 24);
#pragma unroll
            for (int d = 0; d < 8; ++d) {
                sVT[(d     ) * 264 + tid] = v0[d];
                sVT[(d +  8) * 264 + tid] = v1[d];
                sVT[(d + 16) * 264 + tid] = v2[d];
                sVT[(d + 24) * 264 + tid] = v3[d];
            }
        }
        __syncthreads();                    // sVT block-shared: barrier required

        bf16x8 aq[4];
#pragma unroll
        for (int i = 0; i < 4; ++i)
            aq[i] = *(const bf16x8*)(qb + (wave * 64 + i * 16 + l16) * 32 + quad * 8);

        f32x4 o0[4], o1[4], os[4];
#pragma unroll
        for (int i = 0; i < 4; ++i) { o0[i] = zf; o1[i] = zf; os[i] = zf; }

        for (int nc = 0; nc < 4; ++nc) {
            bf16x8 bk[4];
#pragma unroll
            for (int j = 0; j < 4; ++j)
                bk[j] = *(const bf16x8*)(kb + (nc * 64 + j * 16 + l16) * 32 + quad * 8);
            bf16x8 vbf[2][2];
#pragma unroll
            for (int kk = 0; kk < 2; ++kk)
#pragma unroll
                for (int j2 = 0; j2 < 2; ++j2)
                    vbf[kk][j2] = *(const bf16x8*)&sVT[(j2 * 16 + l16) * 264 + nc * 64 + kk * 32 + quad * 8];

#pragma unroll
            for (int i = 0; i < 4; ++i) {
                f32x4 sa[4] = {zf, zf, zf, zf};
#pragma unroll
                for (int j = 0; j < 4; ++j)
                    sa[j] = MFMA16(aq[i], bk[j], sa[j]);
#pragma unroll
                for (int j = 0; j < 4; ++j)
#pragma unroll
                    for (int r = 0; r < 4; ++r)
                        sP[(quad * 4 + r) * 72 + j * 16 + l16] = pkb(__expf(sa[j][r]));
                // sP is wave-private: lgkmcnt ordering suffices (R2-proven)
#pragma unroll
                for (int kk = 0; kk < 2; ++kk) {
                    const bf16x8 pa = *(const bf16x8*)&sP[l16 * 72 + kk * 32 + quad * 8];
                    o0[i] = MFMA16(pa, vbf[kk][0], o0[i]);
                    o1[i] = MFMA16(pa, vbf[kk][1], o1[i]);
                    os[i] = MFMA16(pa, vone, os[i]);
                }
            }
        }

#pragma unroll
        for (int i = 0; i < 4; ++i)
#pragma unroll
            for (int r = 0; r < 4; ++r) {
                const int s = wave * 64 + i * 16 + quad * 4 + r;
                const int tok = base_tok + (s >> 4) * 1024 + (s & 15) * 8;
                const float inv = 1.f / os[i][r];
                const float a0 = o0[i][r] * inv, a1 = o1[i][r] * inv;
                const float b0 = __shfl_xor(a0, 1), b1 = __shfl_xor(a1, 1);
                if (evenL) {
                    *(unsigned*)&attn[(long)tok * 256 + ch + l16]      = pk2(a0, b0);
                    *(unsigned*)&attn[(long)tok * 256 + ch + 16 + l16] = pk2(a1, b1);
                }
            }
    } else {
        // ================= window (local) attention =================
        short* sVT = smem + wave * 2304;          // per-wave [32*72]
        short* sP  = smem + 9216 + wave * 1152;   // per-wave [16*72]
        const int sh   = (blockIdx.x - 2048) * 4 + wave;   // < 8192
        const int head = sh & 3;
        const int win  = (sh >> 2) & 255;
        const int b    = sh >> 10;
        const int base_tok = b * 16384 + (win >> 4) * 1024 + (win & 15) * 8;
        const int ch = head * 32;
        const short* qb = qkvL + (long)sh * 6144;
        const short* kb = qb + 2048;
        const short* vp = qb + 4096;

        // stage V^T: lane = token, full 32-ch row (coalesced)
        {
            bf16x8 v0 = *(const bf16x8*)(vp + lane * 32);
            bf16x8 v1 = *(const bf16x8*)(vp + lane * 32 + 8);
            bf16x8 v2 = *(const bf16x8*)(vp + lane * 32 + 16);
            bf16x8 v3 = *(const bf16x8*)(vp + lane * 32 + 24);
#pragma unroll
            for (int d = 0; d < 8; ++d) {
                sVT[(d     ) * 72 + lane] = v0[d];
                sVT[(d +  8) * 72 + lane] = v1[d];
                sVT[(d + 16) * 72 + lane] = v2[d];
                sVT[(d + 24) * 72 + lane] = v3[d];
            }
        }
        __syncthreads();

        bf16x8 aq[4], bk[4];
#pragma unroll
        for (int i = 0; i < 4; ++i)
            aq[i] = *(const bf16x8*)(qb + (i * 16 + l16) * 32 + quad * 8);
#pragma unroll
        for (int j = 0; j < 4; ++j)
            bk[j] = *(const bf16x8*)(kb + (j * 16 + l16) * 32 + quad * 8);

        bf16x8 vbf[2][2];
#pragma unroll
        for (int kk = 0; kk < 2; ++kk)
#pragma unroll
            for (int j2 = 0; j2 < 2; ++j2)
                vbf[kk][j2] = *(const bf16x8*)&sVT[(j2 * 16 + l16) * 72 + kk * 32 + quad * 8];

#pragma unroll
        for (int i = 0; i < 4; ++i) {
            f32x4 sa[4] = {zf, zf, zf, zf};
#pragma unroll
            for (int j = 0; j < 4; ++j)
                sa[j] = MFMA16(aq[i], bk[j], sa[j]);
#pragma unroll
            for (int j = 0; j < 4; ++j)
#pragma unroll
                for (int r = 0; r < 4; ++r)
                    sP[(quad * 4 + r) * 72 + j * 16 + l16] = pkb(__expf(sa[j][r]));
            // sP is wave-private: lgkmcnt ordering suffices

            f32x4 o0 = zf, o1 = zf, os = zf;
#pragma unroll
            for (int kk = 0; kk < 2; ++kk) {
                const bf16x8 pa = *(const bf16x8*)&sP[l16 * 72 + kk * 32 + quad * 8];
                o0 = MFMA16(pa, vbf[kk][0], o0);
                o1 = MFMA16(pa, vbf[kk][1], o1);
                os = MFMA16(pa, vone, os);
            }

#pragma unroll
            for (int r = 0; r < 4; ++r) {
                const int s = i * 16 + quad * 4 + r;
                const int tok = base_tok + (s >> 3) * 128 + (s & 7);
                const float inv = 1.f / os[r];
                const float a0 = o0[r] * inv, a1 = o1[r] * inv;
                const float b0 = __shfl_xor(a0, 1), b1 = __shfl_xor(a1, 1);
                if (evenL) {
                    *(unsigned*)&attn[(long)tok * 256 + ch + l16]      = pk2(a0, b0);
                    *(unsigned*)&attn[(long)tok * 256 + ch + 16 + l16] = pk2(a1, b1);
                }
            }
        }
    }
}

// ---------------- launch ----------------
extern "C" void kernel_launch(void* const* d_in, const int* in_sizes, int n_in,
                              void* d_out, int out_size, void* d_ws, size_t ws_size,
                              hipStream_t stream) {
    const float* x     = (const float*)d_in[0];
    const float* wqkv  = (const float*)d_in[1];
    const float* wproj = (const float*)d_in[2];
    const float* bproj = (const float*)d_in[3];

    char* ws = (char*)d_ws;
    short* wqT  = (short*)(ws +  67108864);     //     393,216 B (q cols pre-scaled)
    short* wpT  = (short*)(ws +  67502080);     //     131,072 B
    short* qkvL = (short*)(ws +  67633152);     // 100,663,296 B  [8192][3][64][32]
    short* qkvG = (short*)(ws + 168296448);     // 100,663,296 B  [2048][3][256][32]
    short* attn = (short*)(ws + 268959744);     //  67,108,864 B  [131072][256]
    float* out  = (float*)d_out;

    cast_w_kernel<<<dim3(1024), dim3(256), 0, stream>>>(wqkv, wproj, wqT, wpT);
    gemm_qkv_kernel<<<dim3(6144), dim3(256), 0, stream>>>(x, wqT, qkvL, qkvG);
    attn_kernel<<<dim3(4096), dim3(256), 0, stream>>>(qkvL, qkvG, attn);
    gemm_proj_kernel<<<dim3(2048), dim3(256), 0, stream>>>(attn, wpT, out, bproj);
}

// Round 7
// 442.147 us; speedup vs baseline: 1.0685x; 1.0685x over previous
//
#include <hip/hip_runtime.h>
#include <hip/hip_bf16.h>

using bf16x8 = __attribute__((ext_vector_type(8))) short;
using f32x4  = __attribute__((ext_vector_type(4))) float;

#define MFMA16(a, b, c) __builtin_amdgcn_mfma_f32_16x16x32_bf16((a), (b), (c), 0, 0, 0)

__device__ __forceinline__ short f2b(float f) {   // RNE bf16
    unsigned u = __builtin_bit_cast(unsigned, f);
    u = (u + 0x7fffu + ((u >> 16) & 1u)) >> 16;
    return (short)u;
}
__device__ __forceinline__ short pkb(float f) {   // round-to-nearest, ties away
    return (short)((__builtin_bit_cast(unsigned, f) + 0x8000u) >> 16);
}
__device__ __forceinline__ unsigned pk2(float lo, float hi) {  // two bf16 -> dword
    return (unsigned)(unsigned short)pkb(lo) | ((unsigned)(unsigned short)pkb(hi) << 16);
}
__device__ __forceinline__ void gl_lds16(const short* g, short* l) {
    __builtin_amdgcn_global_load_lds(
        (const __attribute__((address_space(1))) unsigned int*)g,
        (__attribute__((address_space(3))) unsigned int*)l, 16, 0, 0);
}

// ---------------- fused cast kernel: x (blocks 0..32767) + weights (blocks 32768..33791) ----------------
__global__ __launch_bounds__(256)
void cast_kernel(const float* __restrict__ x, const float* __restrict__ wqkv,
                 const float* __restrict__ wproj,
                 short* __restrict__ xb, short* __restrict__ wqT, short* __restrict__ wpT) {
    const int bid = blockIdx.x;
    if (bid < 32768) {
        const int i = bid * 256 + threadIdx.x;   // float4 index, grid exact
        const float4 v = ((const float4*)x)[i];
        short4 o;
        o.x = f2b(v.x); o.y = f2b(v.y); o.z = f2b(v.z); o.w = f2b(v.w);
        ((short4*)xb)[i] = o;
    } else {
        const int t = (bid - 32768) * 256 + threadIdx.x;
        if (t < 768 * 256) {
            const int n = t >> 8, k = t & 255;
            float v = wqkv[k * 768 + n];
            if (n < 256) v *= 0.17677669529663687f;    // fold 1/sqrt(hd) into q columns
            wqT[t] = f2b(v);
        } else {
            const int u = t - 768 * 256;               // u < 65536
            const int n = u >> 8, k = u & 255;
            wpT[u] = f2b(wproj[k * 256 + n]);
        }
    }
}

// ---------------- QKV GEMM: R4-proven K-loop + two-half epilogue (LDS 32 KB -> 5 blocks/CU) ----------------
__global__ __launch_bounds__(256)
void gemm_qkv_kernel(const short* __restrict__ A, const short* __restrict__ Bt,
                     short* __restrict__ qkvL, short* __restrict__ qkvG) {
    __shared__ __align__(16) short smem[16384];  // 32768 B: 2x(A 4096|B 4096); epilogue Cs 64x136
    const int tid  = threadIdx.x;
    const int lane = tid & 63, wave = tid >> 6;
    const int wm = wave >> 1, wn = wave & 1;
    const int quad = lane >> 4, l16 = lane & 15;
    const int id = blockIdx.x;
    const int qq = id >> 3, xcd = id & 7;
    const int m0 = (xcd * 128 + qq / 6) * 128;
    const int n0 = (qq % 6) * 128;

    const f32x4 zf = {0.f, 0.f, 0.f, 0.f};
    f32x4 acc[4][4];
#pragma unroll
    for (int i = 0; i < 4; ++i)
#pragma unroll
        for (int j = 0; j < 4; ++j) acc[i][j] = zf;

    const int srow = wave * 16 + (lane >> 2);
    const int scol = ((lane & 3) ^ ((lane >> 3) & 3)) * 8;   // pre-swizzled global source
    const short* Ap = A  + (long)(m0 + srow) * 256 + scol;
    const short* Bp = Bt + (long)(n0 + srow) * 256 + scol;

    auto STAGE = [&](int buf, int kt) {
        short* lA = smem + buf * 8192 + wave * 512;
        const int off = kt * 32;
        gl_lds16(Ap + off,            lA);
        gl_lds16(Ap + 64 * 256 + off, lA + 2048);
        gl_lds16(Bp + off,            lA + 4096);
        gl_lds16(Bp + 64 * 256 + off, lA + 6144);
    };
    const int sw = (l16 >> 1) & 3;                           // read-side swizzle
    auto COMPUTE = [&](int buf) {
        const short* As = smem + buf * 8192;
        const short* Bs = As + 4096;
        bf16x8 af[4], bfr[4];
#pragma unroll
        for (int i = 0; i < 4; ++i)
            af[i] = *(const bf16x8*)&As[(wm * 64 + i * 16 + l16) * 32 + ((quad ^ sw) * 8)];
#pragma unroll
        for (int j = 0; j < 4; ++j)
            bfr[j] = *(const bf16x8*)&Bs[(wn * 64 + j * 16 + l16) * 32 + ((quad ^ sw) * 8)];
#pragma unroll
        for (int i = 0; i < 4; ++i)
#pragma unroll
            for (int j = 0; j < 4; ++j)
                acc[i][j] = MFMA16(af[i], bfr[j], acc[i][j]);
    };

    STAGE(0, 0);
    for (int kt = 0; kt < 8; ++kt) {
        __syncthreads();               // drains vmcnt(0): current buf ready; prev reads done
        if (kt < 7) STAGE((kt + 1) & 1, kt + 1);   // next tile overlaps current compute
        COMPUTE(kt & 1);
    }

    // ---- epilogue in two 64-row halves: Cs[64][136] = 17.4 KB within the 32 KB arena ----
    short* Cs = smem;
    const int part = n0 >> 8;                   // 0=q 1=k 2=v (block-uniform)
    const bool isLocal = ((n0 >> 7) & 1) == 0;  // heads 0..3 vs 4..7
    const int b    = m0 >> 14;
    const int hrow = (m0 >> 7) & 127;
#pragma unroll
    for (int hf = 0; hf < 2; ++hf) {
        __syncthreads();                        // hf=0: K-loop reads done; hf=1: phase-2 reads done
        if (wm == hf) {                         // waves owning tile rows [hf*64, hf*64+64)
            const int ccol = wn * 64 + l16;
#pragma unroll
            for (int i = 0; i < 4; ++i)
#pragma unroll
                for (int j = 0; j < 4; ++j)
#pragma unroll
                    for (int r = 0; r < 4; ++r)
                        Cs[(i * 16 + quad * 4 + r) * 136 + ccol + j * 16] = pkb(acc[i][j][r]);
        }
        __syncthreads();
        if (isLocal) {
            short* dst0 = qkvL + part * 2048;
            const int win_hi = (hrow >> 3) << 4;
            const int ti0    = (hrow & 7) * 8;
            const int t  = lane >> 3;           // 0..7   (ti within chunk)
            const int s4 = (lane & 7) * 4;      // shorts within 32-ch row
#pragma unroll
            for (int c = 0; c < 8; ++c) {
                const int idx = hf * 32 + wave * 8 + c;
                const int wi = idx >> 2, h = idx & 3;     // wi in [hf*8, hf*8+8)
                const ushort4 v = *(const ushort4*)&Cs[((wi & 7) * 8 + t) * 136 + h * 32 + s4];
                short* dp = dst0 + (long)(((b << 8) | (win_hi | wi)) * 4 + h) * 6144 + ti0 * 32;
                *(ushort4*)&dp[lane * 4] = v;   // 512 B contiguous per chunk
            }
        } else {
            const int pos0 = (hrow & 7) * 8;
            const int tib  = (hrow >> 3) * 16;
            const int tt = lane >> 2;           // 0..15  (ti within chunk)
            const int s8 = (lane & 3) * 8;
            if ((lane >> 5) == hf) {            // lanes whose rows tt fall in this half
                short* dst0 = qkvG + part * 8192;
#pragma unroll
                for (int c = 0; c < 8; ++c) {
                    const int idx = wave * 8 + c;
                    const int p = idx >> 2, h = idx & 3;
                    const bf16x8 v = *(const bf16x8*)&Cs[(p + (tt & 7) * 8) * 136 + h * 32 + s8];
                    short* dp = dst0 + (long)(((b << 6) | (pos0 + p)) * 4 + h) * 24576 + tib * 32;
                    *(bf16x8*)&dp[lane * 8] = v;   // 512 B contiguous per half-chunk
                }
            }
        }
    }
}

// ---------------- proj GEMM: [131072 x 256] x [256 x 256]^T + bias, fp32 out ----------------
__global__ __launch_bounds__(256)
void gemm_proj_kernel(const short* __restrict__ A, const short* __restrict__ Bt,
                      float* __restrict__ C, const float* __restrict__ bias) {
    __shared__ __align__(16) short smem[16384];  // 2 x (A 4096 | B 4096)
    const int tid  = threadIdx.x;
    const int lane = tid & 63, wave = tid >> 6;
    const int wm = wave >> 1, wn = wave & 1;
    const int quad = lane >> 4, l16 = lane & 15;
    const int id = blockIdx.x;
    const int qq = id >> 3, xcd = id & 7;
    const int m0 = (xcd * 128 + (qq >> 1)) * 128;
    const int n0 = (qq & 1) * 128;

    const f32x4 zf = {0.f, 0.f, 0.f, 0.f};
    f32x4 acc[4][4];
#pragma unroll
    for (int i = 0; i < 4; ++i)
#pragma unroll
        for (int j = 0; j < 4; ++j) acc[i][j] = zf;

    const int srow = wave * 16 + (lane >> 2);
    const int scol = ((lane & 3) ^ ((lane >> 3) & 3)) * 8;   // pre-swizzled global source
    const short* Ap = A  + (long)(m0 + srow) * 256 + scol;
    const short* Bp = Bt + (long)(n0 + srow) * 256 + scol;

    auto STAGE = [&](int buf, int kt) {
        short* lA = smem + buf * 8192 + wave * 512;
        const int off = kt * 32;
        gl_lds16(Ap + off,            lA);
        gl_lds16(Ap + 64 * 256 + off, lA + 2048);
        gl_lds16(Bp + off,            lA + 4096);
        gl_lds16(Bp + 64 * 256 + off, lA + 6144);
    };
    const int sw = (l16 >> 1) & 3;
    auto COMPUTE = [&](int buf) {
        const short* As = smem + buf * 8192;
        const short* Bs = As + 4096;
        bf16x8 af[4], bfr[4];
#pragma unroll
        for (int i = 0; i < 4; ++i)
            af[i] = *(const bf16x8*)&As[(wm * 64 + i * 16 + l16) * 32 + ((quad ^ sw) * 8)];
#pragma unroll
        for (int j = 0; j < 4; ++j)
            bfr[j] = *(const bf16x8*)&Bs[(wn * 64 + j * 16 + l16) * 32 + ((quad ^ sw) * 8)];
#pragma unroll
        for (int i = 0; i < 4; ++i)
#pragma unroll
            for (int j = 0; j < 4; ++j)
                acc[i][j] = MFMA16(af[i], bfr[j], acc[i][j]);
    };

    STAGE(0, 0);
    for (int kt = 0; kt < 8; ++kt) {
        __syncthreads();
        if (kt < 7) STAGE((kt + 1) & 1, kt + 1);
        COMPUTE(kt & 1);
    }

#pragma unroll
    for (int i = 0; i < 4; ++i)
#pragma unroll
        for (int r = 0; r < 4; ++r) {
            const long row = m0 + wm * 64 + i * 16 + quad * 4 + r;
#pragma unroll
            for (int j = 0; j < 4; ++j) {
                const int col = n0 + wn * 64 + j * 16 + l16;
                C[row * 256 + col] = acc[i][j][r] + bias[col];
            }
        }
}

// ---------------- fused attention kernel (+ T5 setprio around MFMA clusters) ----------------
// blocks [0,2048): grid (global) attention, heads 4..7, seq=256, 1 block/seq-head
// blocks [2048,4096): window (local) attention, heads 0..3, seq=64, 1 wave/seq-head
__global__ __launch_bounds__(256)
void attn_kernel(const short* __restrict__ qkvL, const short* __restrict__ qkvG,
                 short* __restrict__ attn) {
    __shared__ __align__(16) short smem[13824];   // 27648 B -> 5 blocks/CU
    const int tid  = threadIdx.x;
    const int lane = tid & 63, wave = tid >> 6;
    const int quad = lane >> 4, l16 = lane & 15;
    const bf16x8 vone = {0x3F80, 0x3F80, 0x3F80, 0x3F80, 0x3F80, 0x3F80, 0x3F80, 0x3F80};
    const f32x4 zf = {0.f, 0.f, 0.f, 0.f};
    const bool evenL = (l16 & 1) == 0;

    if (blockIdx.x < 2048) {
        // ================= grid (global) attention =================
        short* sVT = smem;                 // [32*264]
        short* sP  = smem + 8448 + wave * 1152;   // per-wave [16*72]
        const int sh   = blockIdx.x;       // < 2048
        const int head = sh & 3;
        const int pos  = (sh >> 2) & 63;
        const int b    = sh >> 8;
        const int base_tok = b * 16384 + (pos >> 3) * 128 + (pos & 7);
        const int ch = (4 + head) * 32;
        const short* qb = qkvG + (long)sh * 24576;
        const short* kb = qb + 8192;
        const short* vp = qb + 16384;

        // stage V^T: thread = token (coalesced)
        {
            bf16x8 v0 = *(const bf16x8*)(vp + tid * 32);
            bf16x8 v1 = *(const bf16x8*)(vp + tid * 32 + 8);
            bf16x8 v2 = *(const bf16x8*)(vp + tid * 32 + 16);
            bf16x8 v3 = *(const bf16x8*)(vp + tid * 32 + 24);
#pragma unroll
            for (int d = 0; d < 8; ++d) {
                sVT[(d     ) * 264 + tid] = v0[d];
                sVT[(d +  8) * 264 + tid] = v1[d];
                sVT[(d + 16) * 264 + tid] = v2[d];
                sVT[(d + 24) * 264 + tid] = v3[d];
            }
        }
        __syncthreads();                    // sVT block-shared: barrier required

        bf16x8 aq[4];
#pragma unroll
        for (int i = 0; i < 4; ++i)
            aq[i] = *(const bf16x8*)(qb + (wave * 64 + i * 16 + l16) * 32 + quad * 8);

        f32x4 o0[4], o1[4], os[4];
#pragma unroll
        for (int i = 0; i < 4; ++i) { o0[i] = zf; o1[i] = zf; os[i] = zf; }

        for (int nc = 0; nc < 4; ++nc) {
            bf16x8 bk[4];
#pragma unroll
            for (int j = 0; j < 4; ++j)
                bk[j] = *(const bf16x8*)(kb + (nc * 64 + j * 16 + l16) * 32 + quad * 8);
            bf16x8 vbf[2][2];
#pragma unroll
            for (int kk = 0; kk < 2; ++kk)
#pragma unroll
                for (int j2 = 0; j2 < 2; ++j2)
                    vbf[kk][j2] = *(const bf16x8*)&sVT[(j2 * 16 + l16) * 264 + nc * 64 + kk * 32 + quad * 8];

#pragma unroll
            for (int i = 0; i < 4; ++i) {
                f32x4 sa[4] = {zf, zf, zf, zf};
                __builtin_amdgcn_s_setprio(1);
#pragma unroll
                for (int j = 0; j < 4; ++j)
                    sa[j] = MFMA16(aq[i], bk[j], sa[j]);
                __builtin_amdgcn_s_setprio(0);
#pragma unroll
                for (int j = 0; j < 4; ++j)
#pragma unroll
                    for (int r = 0; r < 4; ++r)
                        sP[(quad * 4 + r) * 72 + j * 16 + l16] = pkb(__expf(sa[j][r]));
                // sP is wave-private: lgkmcnt ordering suffices (R2-proven)
                __builtin_amdgcn_s_setprio(1);
#pragma unroll
                for (int kk = 0; kk < 2; ++kk) {
                    const bf16x8 pa = *(const bf16x8*)&sP[l16 * 72 + kk * 32 + quad * 8];
                    o0[i] = MFMA16(pa, vbf[kk][0], o0[i]);
                    o1[i] = MFMA16(pa, vbf[kk][1], o1[i]);
                    os[i] = MFMA16(pa, vone, os[i]);
                }
                __builtin_amdgcn_s_setprio(0);
            }
        }

#pragma unroll
        for (int i = 0; i < 4; ++i)
#pragma unroll
            for (int r = 0; r < 4; ++r) {
                const int s = wave * 64 + i * 16 + quad * 4 + r;
                const int tok = base_tok + (s >> 4) * 1024 + (s & 15) * 8;
                const float inv = 1.f / os[i][r];
                const float a0 = o0[i][r] * inv, a1 = o1[i][r] * inv;
                const float b0 = __shfl_xor(a0, 1), b1 = __shfl_xor(a1, 1);
                if (evenL) {
                    *(unsigned*)&attn[(long)tok * 256 + ch + l16]      = pk2(a0, b0);
                    *(unsigned*)&attn[(long)tok * 256 + ch + 16 + l16] = pk2(a1, b1);
                }
            }
    } else {
        // ================= window (local) attention =================
        short* sVT = smem + wave * 2304;          // per-wave [32*72]
        short* sP  = smem + 9216 + wave * 1152;   // per-wave [16*72]
        const int sh   = (blockIdx.x - 2048) * 4 + wave;   // < 8192
        const int head = sh & 3;
        const int win  = (sh >> 2) & 255;
        const int b    = sh >> 10;
        const int base_tok = b * 16384 + (win >> 4) * 1024 + (win & 15) * 8;
        const int ch = head * 32;
        const short* qb = qkvL + (long)sh * 6144;
        const short* kb = qb + 2048;
        const short* vp = qb + 4096;

        // stage V^T: lane = token, full 32-ch row (coalesced)
        {
            bf16x8 v0 = *(const bf16x8*)(vp + lane * 32);
            bf16x8 v1 = *(const bf16x8*)(vp + lane * 32 + 8);
            bf16x8 v2 = *(const bf16x8*)(vp + lane * 32 + 16);
            bf16x8 v3 = *(const bf16x8*)(vp + lane * 32 + 24);
#pragma unroll
            for (int d = 0; d < 8; ++d) {
                sVT[(d     ) * 72 + lane] = v0[d];
                sVT[(d +  8) * 72 + lane] = v1[d];
                sVT[(d + 16) * 72 + lane] = v2[d];
                sVT[(d + 24) * 72 + lane] = v3[d];
            }
        }
        __syncthreads();

        bf16x8 aq[4], bk[4];
#pragma unroll
        for (int i = 0; i < 4; ++i)
            aq[i] = *(const bf16x8*)(qb + (i * 16 + l16) * 32 + quad * 8);
#pragma unroll
        for (int j = 0; j < 4; ++j)
            bk[j] = *(const bf16x8*)(kb + (j * 16 + l16) * 32 + quad * 8);

        bf16x8 vbf[2][2];
#pragma unroll
        for (int kk = 0; kk < 2; ++kk)
#pragma unroll
            for (int j2 = 0; j2 < 2; ++j2)
                vbf[kk][j2] = *(const bf16x8*)&sVT[(j2 * 16 + l16) * 72 + kk * 32 + quad * 8];

#pragma unroll
        for (int i = 0; i < 4; ++i) {
            f32x4 sa[4] = {zf, zf, zf, zf};
            __builtin_amdgcn_s_setprio(1);
#pragma unroll
            for (int j = 0; j < 4; ++j)
                sa[j] = MFMA16(aq[i], bk[j], sa[j]);
            __builtin_amdgcn_s_setprio(0);
#pragma unroll
            for (int j = 0; j < 4; ++j)
#pragma unroll
                for (int r = 0; r < 4; ++r)
                    sP[(quad * 4 + r) * 72 + j * 16 + l16] = pkb(__expf(sa[j][r]));
            // sP is wave-private: lgkmcnt ordering suffices

            f32x4 o0 = zf, o1 = zf, os = zf;
            __builtin_amdgcn_s_setprio(1);
#pragma unroll
            for (int kk = 0; kk < 2; ++kk) {
                const bf16x8 pa = *(const bf16x8*)&sP[l16 * 72 + kk * 32 + quad * 8];
                o0 = MFMA16(pa, vbf[kk][0], o0);
                o1 = MFMA16(pa, vbf[kk][1], o1);
                os = MFMA16(pa, vone, os);
            }
            __builtin_amdgcn_s_setprio(0);

#pragma unroll
            for (int r = 0; r < 4; ++r) {
                const int s = i * 16 + quad * 4 + r;
                const int tok = base_tok + (s >> 3) * 128 + (s & 7);
                const float inv = 1.f / os[r];
                const float a0 = o0[r] * inv, a1 = o1[r] * inv;
                const float b0 = __shfl_xor(a0, 1), b1 = __shfl_xor(a1, 1);
                if (evenL) {
                    *(unsigned*)&attn[(long)tok * 256 + ch + l16]      = pk2(a0, b0);
                    *(unsigned*)&attn[(long)tok * 256 + ch + 16 + l16] = pk2(a1, b1);
                }
            }
        }
    }
}

// ---------------- launch ----------------
extern "C" void kernel_launch(void* const* d_in, const int* in_sizes, int n_in,
                              void* d_out, int out_size, void* d_ws, size_t ws_size,
                              hipStream_t stream) {
    const float* x     = (const float*)d_in[0];
    const float* wqkv  = (const float*)d_in[1];
    const float* wproj = (const float*)d_in[2];
    const float* bproj = (const float*)d_in[3];

    char* ws = (char*)d_ws;
    short* xb   = (short*)(ws);                 //  67,108,864 B
    short* wqT  = (short*)(ws +  67108864);     //     393,216 B (q cols pre-scaled)
    short* wpT  = (short*)(ws +  67502080);     //     131,072 B
    short* qkvL = (short*)(ws +  67633152);     // 100,663,296 B  [8192][3][64][32]
    short* qkvG = (short*)(ws + 168296448);     // 100,663,296 B  [2048][3][256][32]
    short* attn = (short*)(ws + 268959744);     //  67,108,864 B  [131072][256]
    float* out  = (float*)d_out;

    cast_kernel<<<dim3(33792), dim3(256), 0, stream>>>(x, wqkv, wproj, xb, wqT, wpT);
    gemm_qkv_kernel<<<dim3(6144), dim3(256), 0, stream>>>(xb, wqT, qkvL, qkvG);
    attn_kernel<<<dim3(4096), dim3(256), 0, stream>>>(qkvL, qkvG, attn);
    gemm_proj_kernel<<<dim3(2048), dim3(256), 0, stream>>>(attn, wpT, out, bproj);
}

// Round 8
// 431.035 us; speedup vs baseline: 1.0961x; 1.0258x over previous
//
#include <hip/hip_runtime.h>
#include <hip/hip_bf16.h>

using bf16x8 = __attribute__((ext_vector_type(8))) short;
using f32x4  = __attribute__((ext_vector_type(4))) float;

#define MFMA16(a, b, c) __builtin_amdgcn_mfma_f32_16x16x32_bf16((a), (b), (c), 0, 0, 0)

__device__ __forceinline__ short f2b(float f) {   // RNE bf16
    unsigned u = __builtin_bit_cast(unsigned, f);
    u = (u + 0x7fffu + ((u >> 16) & 1u)) >> 16;
    return (short)u;
}
__device__ __forceinline__ short pkb(float f) {   // round-to-nearest, ties away
    return (short)((__builtin_bit_cast(unsigned, f) + 0x8000u) >> 16);
}
__device__ __forceinline__ unsigned pk2(float lo, float hi) {  // two bf16 -> dword
    return (unsigned)(unsigned short)pkb(lo) | ((unsigned)(unsigned short)pkb(hi) << 16);
}
__device__ __forceinline__ void gl_lds16(const short* g, short* l) {
    __builtin_amdgcn_global_load_lds(
        (const __attribute__((address_space(1))) unsigned int*)g,
        (__attribute__((address_space(3))) unsigned int*)l, 16, 0, 0);
}

// ---------------- fused cast kernel: x (blocks 0..32767) + weights (blocks 32768..33791) ----------------
__global__ __launch_bounds__(256)
void cast_kernel(const float* __restrict__ x, const float* __restrict__ wqkv,
                 const float* __restrict__ wproj,
                 short* __restrict__ xb, short* __restrict__ wqT, short* __restrict__ wpT) {
    const int bid = blockIdx.x;
    if (bid < 32768) {
        const int i = bid * 256 + threadIdx.x;   // float4 index, grid exact
        const float4 v = ((const float4*)x)[i];
        short4 o;
        o.x = f2b(v.x); o.y = f2b(v.y); o.z = f2b(v.z); o.w = f2b(v.w);
        ((short4*)xb)[i] = o;
    } else {
        const int t = (bid - 32768) * 256 + threadIdx.x;
        if (t < 768 * 256) {
            const int n = t >> 8, k = t & 255;
            float v = wqkv[k * 768 + n];
            if (n < 256) v *= 0.17677669529663687f;    // fold 1/sqrt(hd) into q columns
            wqT[t] = f2b(v);
        } else {
            const int u = t - 768 * 256;               // u < 65536
            const int n = u >> 8, k = u & 255;
            wpT[u] = f2b(wproj[k * 256 + n]);
        }
    }
}

// ---------------- QKV GEMM: R4-proven (syncthreads-dbuf + swizzle, one-shot epilogue) ----------------
__global__ __launch_bounds__(256)
void gemm_qkv_kernel(const short* __restrict__ A, const short* __restrict__ Bt,
                     short* __restrict__ qkvL, short* __restrict__ qkvG) {
    __shared__ __align__(16) short smem[128 * 136];  // 34816 B: staging 2x8KB dbuf, epilogue Cs
    const int tid  = threadIdx.x;
    const int lane = tid & 63, wave = tid >> 6;
    const int wm = wave >> 1, wn = wave & 1;
    const int quad = lane >> 4, l16 = lane & 15;
    const int id = blockIdx.x;
    const int qq = id >> 3, xcd = id & 7;
    const int m0 = (xcd * 128 + qq / 6) * 128;
    const int n0 = (qq % 6) * 128;

    const f32x4 zf = {0.f, 0.f, 0.f, 0.f};
    f32x4 acc[4][4];
#pragma unroll
    for (int i = 0; i < 4; ++i)
#pragma unroll
        for (int j = 0; j < 4; ++j) acc[i][j] = zf;

    const int srow = wave * 16 + (lane >> 2);
    const int scol = ((lane & 3) ^ ((lane >> 3) & 3)) * 8;   // pre-swizzled global source
    const short* Ap = A  + (long)(m0 + srow) * 256 + scol;
    const short* Bp = Bt + (long)(n0 + srow) * 256 + scol;

    auto STAGE = [&](int buf, int kt) {
        short* lA = smem + buf * 8192 + wave * 512;
        const int off = kt * 32;
        gl_lds16(Ap + off,            lA);
        gl_lds16(Ap + 64 * 256 + off, lA + 2048);
        gl_lds16(Bp + off,            lA + 4096);
        gl_lds16(Bp + 64 * 256 + off, lA + 6144);
    };
    const int sw = (l16 >> 1) & 3;                           // read-side swizzle
    auto COMPUTE = [&](int buf) {
        const short* As = smem + buf * 8192;
        const short* Bs = As + 4096;
        bf16x8 af[4], bfr[4];
#pragma unroll
        for (int i = 0; i < 4; ++i)
            af[i] = *(const bf16x8*)&As[(wm * 64 + i * 16 + l16) * 32 + ((quad ^ sw) * 8)];
#pragma unroll
        for (int j = 0; j < 4; ++j)
            bfr[j] = *(const bf16x8*)&Bs[(wn * 64 + j * 16 + l16) * 32 + ((quad ^ sw) * 8)];
#pragma unroll
        for (int i = 0; i < 4; ++i)
#pragma unroll
            for (int j = 0; j < 4; ++j)
                acc[i][j] = MFMA16(af[i], bfr[j], acc[i][j]);
    };

    STAGE(0, 0);
    for (int kt = 0; kt < 8; ++kt) {
        __syncthreads();               // drains vmcnt(0): current buf ready; prev reads done
        if (kt < 7) STAGE((kt + 1) & 1, kt + 1);   // next tile overlaps current compute
        COMPUTE(kt & 1);
    }

    // ---- epilogue phase 1: acc -> Cs[128 rows][136] as bf16 ----
    __syncthreads();                            // buffers fully consumed; reuse as Cs
    short* Cs = smem;
    {
        const int crow = wm * 64 + quad * 4;
        const int ccol = wn * 64 + l16;
#pragma unroll
        for (int i = 0; i < 4; ++i)
#pragma unroll
            for (int j = 0; j < 4; ++j)
#pragma unroll
                for (int r = 0; r < 4; ++r)
                    Cs[(crow + i * 16 + r) * 136 + ccol + j * 16] = pkb(acc[i][j][r]);
    }
    __syncthreads();

    // ---- epilogue phase 2: coalesced chunk stores ----
    const int part = n0 >> 8;                   // 0=q 1=k 2=v (block-uniform)
    const bool isLocal = ((n0 >> 7) & 1) == 0;  // heads 0..3 vs 4..7
    const int b    = m0 >> 14;
    const int hrow = (m0 >> 7) & 127;
    if (isLocal) {
        short* dst0 = qkvL + part * 2048;
        const int win_hi = (hrow >> 3) << 4;
        const int ti0    = (hrow & 7) * 8;
        const int t  = lane >> 3;               // 0..7   (ti within chunk)
        const int s4 = (lane & 7) * 4;          // shorts within 32-ch row
#pragma unroll
        for (int c = 0; c < 16; ++c) {
            const int idx = wave * 16 + c;
            const int wi = idx >> 2, h = idx & 3;
            const ushort4 v = *(const ushort4*)&Cs[(wi * 8 + t) * 136 + h * 32 + s4];
            short* dp = dst0 + (long)(((b << 8) | (win_hi | wi)) * 4 + h) * 6144 + ti0 * 32;
            *(ushort4*)&dp[lane * 4] = v;       // 512 B contiguous per chunk
        }
    } else {
        short* dst0 = qkvG + part * 8192;
        const int pos0 = (hrow & 7) * 8;
        const int tib  = (hrow >> 3) * 16;
        const int tt = lane >> 2;               // 0..15  (ti within chunk)
        const int s8 = (lane & 3) * 8;
#pragma unroll
        for (int c = 0; c < 8; ++c) {
            const int idx = wave * 8 + c;
            const int p = idx >> 2, h = idx & 3;
            const bf16x8 v = *(const bf16x8*)&Cs[(p + tt * 8) * 136 + h * 32 + s8];
            short* dp = dst0 + (long)(((b << 6) | (pos0 + p)) * 4 + h) * 24576 + tib * 32;
            *(bf16x8*)&dp[lane * 8] = v;        // 1 KB contiguous per chunk
        }
    }
}

// ---------------- proj GEMM: [131072 x 256] x [256 x 256]^T + bias, fp32 out ----------------
__global__ __launch_bounds__(256)
void gemm_proj_kernel(const short* __restrict__ A, const short* __restrict__ Bt,
                      float* __restrict__ C, const float* __restrict__ bias) {
    __shared__ __align__(16) short smem[16384];  // 2 x (A 4096 | B 4096)
    const int tid  = threadIdx.x;
    const int lane = tid & 63, wave = tid >> 6;
    const int wm = wave >> 1, wn = wave & 1;
    const int quad = lane >> 4, l16 = lane & 15;
    const int id = blockIdx.x;
    const int qq = id >> 3, xcd = id & 7;
    const int m0 = (xcd * 128 + (qq >> 1)) * 128;
    const int n0 = (qq & 1) * 128;

    const f32x4 zf = {0.f, 0.f, 0.f, 0.f};
    f32x4 acc[4][4];
#pragma unroll
    for (int i = 0; i < 4; ++i)
#pragma unroll
        for (int j = 0; j < 4; ++j) acc[i][j] = zf;

    const int srow = wave * 16 + (lane >> 2);
    const int scol = ((lane & 3) ^ ((lane >> 3) & 3)) * 8;   // pre-swizzled global source
    const short* Ap = A  + (long)(m0 + srow) * 256 + scol;
    const short* Bp = Bt + (long)(n0 + srow) * 256 + scol;

    auto STAGE = [&](int buf, int kt) {
        short* lA = smem + buf * 8192 + wave * 512;
        const int off = kt * 32;
        gl_lds16(Ap + off,            lA);
        gl_lds16(Ap + 64 * 256 + off, lA + 2048);
        gl_lds16(Bp + off,            lA + 4096);
        gl_lds16(Bp + 64 * 256 + off, lA + 6144);
    };
    const int sw = (l16 >> 1) & 3;
    auto COMPUTE = [&](int buf) {
        const short* As = smem + buf * 8192;
        const short* Bs = As + 4096;
        bf16x8 af[4], bfr[4];
#pragma unroll
        for (int i = 0; i < 4; ++i)
            af[i] = *(const bf16x8*)&As[(wm * 64 + i * 16 + l16) * 32 + ((quad ^ sw) * 8)];
#pragma unroll
        for (int j = 0; j < 4; ++j)
            bfr[j] = *(const bf16x8*)&Bs[(wn * 64 + j * 16 + l16) * 32 + ((quad ^ sw) * 8)];
#pragma unroll
        for (int i = 0; i < 4; ++i)
#pragma unroll
            for (int j = 0; j < 4; ++j)
                acc[i][j] = MFMA16(af[i], bfr[j], acc[i][j]);
    };

    STAGE(0, 0);
    for (int kt = 0; kt < 8; ++kt) {
        __syncthreads();
        if (kt < 7) STAGE((kt + 1) & 1, kt + 1);
        COMPUTE(kt & 1);
    }

#pragma unroll
    for (int i = 0; i < 4; ++i)
#pragma unroll
        for (int r = 0; r < 4; ++r) {
            const long row = m0 + wm * 64 + i * 16 + quad * 4 + r;
#pragma unroll
            for (int j = 0; j < 4; ++j) {
                const int col = n0 + wn * 64 + j * 16 + l16;
                C[row * 256 + col] = acc[i][j][r] + bias[col];
            }
        }
}

// ---------------- fused attention kernel (+ T5 setprio around MFMA clusters) ----------------
// blocks [0,2048): grid (global) attention, heads 4..7, seq=256, 1 block/seq-head
// blocks [2048,4096): window (local) attention, heads 0..3, seq=64, 1 wave/seq-head
__global__ __launch_bounds__(256)
void attn_kernel(const short* __restrict__ qkvL, const short* __restrict__ qkvG,
                 short* __restrict__ attn) {
    __shared__ __align__(16) short smem[13824];   // 27648 B -> 5 blocks/CU
    const int tid  = threadIdx.x;
    const int lane = tid & 63, wave = tid >> 6;
    const int quad = lane >> 4, l16 = lane & 15;
    const bf16x8 vone = {0x3F80, 0x3F80, 0x3F80, 0x3F80, 0x3F80, 0x3F80, 0x3F80, 0x3F80};
    const f32x4 zf = {0.f, 0.f, 0.f, 0.f};
    const bool evenL = (l16 & 1) == 0;

    if (blockIdx.x < 2048) {
        // ================= grid (global) attention =================
        short* sVT = smem;                 // [32*264]
        short* sP  = smem + 8448 + wave * 1152;   // per-wave [16*72]
        const int sh   = blockIdx.x;       // < 2048
        const int head = sh & 3;
        const int pos  = (sh >> 2) & 63;
        const int b    = sh >> 8;
        const int base_tok = b * 16384 + (pos >> 3) * 128 + (pos & 7);
        const int ch = (4 + head) * 32;
        const short* qb = qkvG + (long)sh * 24576;
        const short* kb = qb + 8192;
        const short* vp = qb + 16384;

        // stage V^T: thread = token (coalesced)
        {
            bf16x8 v0 = *(const bf16x8*)(vp + tid * 32);
            bf16x8 v1 = *(const bf16x8*)(vp + tid * 32 + 8);
            bf16x8 v2 = *(const bf16x8*)(vp + tid * 32 + 16);
            bf16x8 v3 = *(const bf16x8*)(vp + tid * 32 + 24);
#pragma unroll
            for (int d = 0; d < 8; ++d) {
                sVT[(d     ) * 264 + tid] = v0[d];
                sVT[(d +  8) * 264 + tid] = v1[d];
                sVT[(d + 16) * 264 + tid] = v2[d];
                sVT[(d + 24) * 264 + tid] = v3[d];
            }
        }
        __syncthreads();                    // sVT block-shared: barrier required

        bf16x8 aq[4];
#pragma unroll
        for (int i = 0; i < 4; ++i)
            aq[i] = *(const bf16x8*)(qb + (wave * 64 + i * 16 + l16) * 32 + quad * 8);

        f32x4 o0[4], o1[4], os[4];
#pragma unroll
        for (int i = 0; i < 4; ++i) { o0[i] = zf; o1[i] = zf; os[i] = zf; }

        for (int nc = 0; nc < 4; ++nc) {
            bf16x8 bk[4];
#pragma unroll
            for (int j = 0; j < 4; ++j)
                bk[j] = *(const bf16x8*)(kb + (nc * 64 + j * 16 + l16) * 32 + quad * 8);
            bf16x8 vbf[2][2];
#pragma unroll
            for (int kk = 0; kk < 2; ++kk)
#pragma unroll
                for (int j2 = 0; j2 < 2; ++j2)
                    vbf[kk][j2] = *(const bf16x8*)&sVT[(j2 * 16 + l16) * 264 + nc * 64 + kk * 32 + quad * 8];

#pragma unroll
            for (int i = 0; i < 4; ++i) {
                f32x4 sa[4] = {zf, zf, zf, zf};
                __builtin_amdgcn_s_setprio(1);
#pragma unroll
                for (int j = 0; j < 4; ++j)
                    sa[j] = MFMA16(aq[i], bk[j], sa[j]);
                __builtin_amdgcn_s_setprio(0);
#pragma unroll
                for (int j = 0; j < 4; ++j)
#pragma unroll
                    for (int r = 0; r < 4; ++r)
                        sP[(quad * 4 + r) * 72 + j * 16 + l16] = pkb(__expf(sa[j][r]));
                // sP is wave-private: lgkmcnt ordering suffices (R2-proven)
                __builtin_amdgcn_s_setprio(1);
#pragma unroll
                for (int kk = 0; kk < 2; ++kk) {
                    const bf16x8 pa = *(const bf16x8*)&sP[l16 * 72 + kk * 32 + quad * 8];
                    o0[i] = MFMA16(pa, vbf[kk][0], o0[i]);
                    o1[i] = MFMA16(pa, vbf[kk][1], o1[i]);
                    os[i] = MFMA16(pa, vone, os[i]);
                }
                __builtin_amdgcn_s_setprio(0);
            }
        }

#pragma unroll
        for (int i = 0; i < 4; ++i)
#pragma unroll
            for (int r = 0; r < 4; ++r) {
                const int s = wave * 64 + i * 16 + quad * 4 + r;
                const int tok = base_tok + (s >> 4) * 1024 + (s & 15) * 8;
                const float inv = 1.f / os[i][r];
                const float a0 = o0[i][r] * inv, a1 = o1[i][r] * inv;
                const float b0 = __shfl_xor(a0, 1), b1 = __shfl_xor(a1, 1);
                if (evenL) {
                    *(unsigned*)&attn[(long)tok * 256 + ch + l16]      = pk2(a0, b0);
                    *(unsigned*)&attn[(long)tok * 256 + ch + 16 + l16] = pk2(a1, b1);
                }
            }
    } else {
        // ================= window (local) attention =================
        short* sVT = smem + wave * 2304;          // per-wave [32*72]
        short* sP  = smem + 9216 + wave * 1152;   // per-wave [16*72]
        const int sh   = (blockIdx.x - 2048) * 4 + wave;   // < 8192
        const int head = sh & 3;
        const int win  = (sh >> 2) & 255;
        const int b    = sh >> 10;
        const int base_tok = b * 16384 + (win >> 4) * 1024 + (win & 15) * 8;
        const int ch = head * 32;
        const short* qb = qkvL + (long)sh * 6144;
        const short* kb = qb + 2048;
        const short* vp = qb + 4096;

        // stage V^T: lane = token, full 32-ch row (coalesced)
        {
            bf16x8 v0 = *(const bf16x8*)(vp + lane * 32);
            bf16x8 v1 = *(const bf16x8*)(vp + lane * 32 + 8);
            bf16x8 v2 = *(const bf16x8*)(vp + lane * 32 + 16);
            bf16x8 v3 = *(const bf16x8*)(vp + lane * 32 + 24);
#pragma unroll
            for (int d = 0; d < 8; ++d) {
                sVT[(d     ) * 72 + lane] = v0[d];
                sVT[(d +  8) * 72 + lane] = v1[d];
                sVT[(d + 16) * 72 + lane] = v2[d];
                sVT[(d + 24) * 72 + lane] = v3[d];
            }
        }
        __syncthreads();

        bf16x8 aq[4], bk[4];
#pragma unroll
        for (int i = 0; i < 4; ++i)
            aq[i] = *(const bf16x8*)(qb + (i * 16 + l16) * 32 + quad * 8);
#pragma unroll
        for (int j = 0; j < 4; ++j)
            bk[j] = *(const bf16x8*)(kb + (j * 16 + l16) * 32 + quad * 8);

        bf16x8 vbf[2][2];
#pragma unroll
        for (int kk = 0; kk < 2; ++kk)
#pragma unroll
            for (int j2 = 0; j2 < 2; ++j2)
                vbf[kk][j2] = *(const bf16x8*)&sVT[(j2 * 16 + l16) * 72 + kk * 32 + quad * 8];

#pragma unroll
        for (int i = 0; i < 4; ++i) {
            f32x4 sa[4] = {zf, zf, zf, zf};
            __builtin_amdgcn_s_setprio(1);
#pragma unroll
            for (int j = 0; j < 4; ++j)
                sa[j] = MFMA16(aq[i], bk[j], sa[j]);
            __builtin_amdgcn_s_setprio(0);
#pragma unroll
            for (int j = 0; j < 4; ++j)
#pragma unroll
                for (int r = 0; r < 4; ++r)
                    sP[(quad * 4 + r) * 72 + j * 16 + l16] = pkb(__expf(sa[j][r]));
            // sP is wave-private: lgkmcnt ordering suffices

            f32x4 o0 = zf, o1 = zf, os = zf;
            __builtin_amdgcn_s_setprio(1);
#pragma unroll
            for (int kk = 0; kk < 2; ++kk) {
                const bf16x8 pa = *(const bf16x8*)&sP[l16 * 72 + kk * 32 + quad * 8];
                o0 = MFMA16(pa, vbf[kk][0], o0);
                o1 = MFMA16(pa, vbf[kk][1], o1);
                os = MFMA16(pa, vone, os);
            }
            __builtin_amdgcn_s_setprio(0);

#pragma unroll
            for (int r = 0; r < 4; ++r) {
                const int s = i * 16 + quad * 4 + r;
                const int tok = base_tok + (s >> 3) * 128 + (s & 7);
                const float inv = 1.f / os[r];
                const float a0 = o0[r] * inv, a1 = o1[r] * inv;
                const float b0 = __shfl_xor(a0, 1), b1 = __shfl_xor(a1, 1);
                if (evenL) {
                    *(unsigned*)&attn[(long)tok * 256 + ch + l16]      = pk2(a0, b0);
                    *(unsigned*)&attn[(long)tok * 256 + ch + 16 + l16] = pk2(a1, b1);
                }
            }
        }
    }
}

// ---------------- launch ----------------
extern "C" void kernel_launch(void* const* d_in, const int* in_sizes, int n_in,
                              void* d_out, int out_size, void* d_ws, size_t ws_size,
                              hipStream_t stream) {
    const float* x     = (const float*)d_in[0];
    const float* wqkv  = (const float*)d_in[1];
    const float* wproj = (const float*)d_in[2];
    const float* bproj = (const float*)d_in[3];

    char* ws = (char*)d_ws;
    short* xb   = (short*)(ws);                 //  67,108,864 B
    short* wqT  = (short*)(ws +  67108864);     //     393,216 B (q cols pre-scaled)
    short* wpT  = (short*)(ws +  67502080);     //     131,072 B
    short* qkvL = (short*)(ws +  67633152);     // 100,663,296 B  [8192][3][64][32]
    short* qkvG = (short*)(ws + 168296448);     // 100,663,296 B  [2048][3][256][32]
    short* attn = (short*)(ws + 268959744);     //  67,108,864 B  [131072][256]
    float* out  = (float*)d_out;

    cast_kernel<<<dim3(33792), dim3(256), 0, stream>>>(x, wqkv, wproj, xb, wqT, wpT);
    gemm_qkv_kernel<<<dim3(6144), dim3(256), 0, stream>>>(xb, wqT, qkvL, qkvG);
    attn_kernel<<<dim3(4096), dim3(256), 0, stream>>>(qkvL, qkvG, attn);
    gemm_proj_kernel<<<dim3(2048), dim3(256), 0, stream>>>(attn, wpT, out, bproj);
}